// Round 6
// baseline (319.524 us; speedup 1.0000x reference)
//
#include <hip/hip_runtime.h>
#include <math.h>
#include <limits.h>

// ---- problem constants ----
#define C_IN 256
#define HM_H 136
#define HM_W 240
#define HM_N (HM_H * HM_W)      // 32640
#define MB   64
#define MH   272
#define MW   480
#define MN   (MH * MW)          // 130560
#define NP   134
#define NI   4
#define HID  64

// d_out layout (floats): scores[4] | inds[4] | regs0[4*MN] | masks0[4*MN] | feat[4*480*2]
#define REG_OFF   8
#define MASK_OFF  (8 + NI * MN)
#define FEAT_OFF  (8 + 2 * NI * MN)

// ws layout (floats): hm[32640] | cand_v[512]+cand_i[512] | gp[536] | wt @ 65824
#define WS_HM   0
#define WS_CV   HM_N
#define WS_CI   (HM_N + 512)
#define WS_GP   (2 * HM_N)
#define WS_WT_F 65824

typedef float  f32x4  __attribute__((ext_vector_type(4)));
typedef short  bf16x8 __attribute__((ext_vector_type(8)));
typedef unsigned short u16x8 __attribute__((ext_vector_type(8)));

__device__ __forceinline__ unsigned short f2bf(float f) {
  unsigned int u = __float_as_uint(f);
  u += 0x7FFFu + ((u >> 16) & 1u);
  return (unsigned short)(u >> 16);
}
__device__ __forceinline__ float b2f(unsigned short h) {
  return __uint_as_float(((unsigned int)h) << 16);
}

__device__ __forceinline__ void glds16(const void* g, void* l) {
  __builtin_amdgcn_global_load_lds(
      (const __attribute__((address_space(1))) unsigned int*)g,
      (__attribute__((address_space(3))) unsigned int*)l, 16, 0, 0);
}

// ------------------------------------------------------------------
// K0: merged weight-prep + heatmap.
// ------------------------------------------------------------------
__global__ void k_prep(const float* __restrict__ mb_w, unsigned short* __restrict__ wt,
                       const float* __restrict__ out1, const float* __restrict__ hm_w,
                       const float* __restrict__ hm_b, float* __restrict__ ws_hm) {
  __shared__ float part[4][64];
  if (blockIdx.x < 576) {
    int idx = blockIdx.x * 256 + threadIdx.x;     // 147456 total
    int j    = idx & 7;
    int lane = (idx >> 3) & 63;
    int nt   = (idx >> 9) & 3;
    int gt   = idx >> 11;
    int t    = gt % 9;
    int g    = gt / 9;
    int n = nt * 16 + (lane & 15);
    int c = g * 32 + (lane >> 4) * 8 + j;
    wt[idx] = f2bf(mb_w[(n * C_IN + c) * 9 + t]);
  } else {
    int b = blockIdx.x - 576, t = threadIdx.x;
    int cg = t >> 6, pl = t & 63;
    int p = b * 64 + pl;                         // 510*64 = 32640
    float s = 0.f;
    #pragma unroll 16
    for (int c = 0; c < 64; ++c)
      s += hm_w[cg * 64 + c] * out1[(cg * 64 + c) * HM_N + p];
    part[cg][pl] = s;
    __syncthreads();
    if (t < 64) {
      float tot = part[0][t] + part[1][t] + part[2][t] + part[3][t] + hm_b[0];
      float sig = 1.f / (1.f + expf(-tot));
      sig = fminf(fmaxf(sig, 1e-4f), 1.f - 1e-4f);
      ws_hm[b * 64 + t] = sig;
    }
  }
}

// ------------------------------------------------------------------
// top-4 list merge helpers
// ------------------------------------------------------------------
__device__ __forceinline__ bool better(float av, int ai, float bv, int bi) {
  return (av > bv) || (av == bv && ai < bi);
}

template<int NTHR>
__device__ void top4_tree(float* sv, int* si, int t) {
  for (int s = NTHR / 2; s >= 1; s >>= 1) {
    if (t < s) {
      float a[4], b[4]; int ai[4], bj[4];
      #pragma unroll
      for (int k = 0; k < 4; ++k) {
        a[k] = sv[t * 4 + k];        ai[k] = si[t * 4 + k];
        b[k] = sv[(t + s) * 4 + k];  bj[k] = si[(t + s) * 4 + k];
      }
      float ov[4]; int oi[4];
      int i = 0, j = 0;
      #pragma unroll
      for (int k = 0; k < 4; ++k) {
        if (better(a[i], ai[i], b[j], bj[j])) { ov[k] = a[i]; oi[k] = ai[i]; ++i; }
        else                                   { ov[k] = b[j]; oi[k] = bj[j]; ++j; }
      }
      #pragma unroll
      for (int k = 0; k < 4; ++k) { sv[t * 4 + k] = ov[k]; si[t * 4 + k] = oi[k]; }
    }
    __syncthreads();
  }
}

// ------------------------------------------------------------------
// K2a: fused NMS + per-block top-4 (128 blocks x 255 pixels)
// ------------------------------------------------------------------
__global__ void k_nms_top(const float* __restrict__ ws_hm, float* __restrict__ candv,
                          int* __restrict__ candi) {
  __shared__ float sv[256 * 4];
  __shared__ int   si[256 * 4];
  int b = blockIdx.x, t = threadIdx.x;
  float v = -1.f; int idx = INT_MAX;
  if (t < 255) {
    int p = b * 255 + t;
    int y = p / HM_W, x = p - y * HM_W;
    float c = ws_hm[p], m = c;
    #pragma unroll
    for (int dy = -1; dy <= 1; ++dy)
      #pragma unroll
      for (int dx = -1; dx <= 1; ++dx) {
        int yy = y + dy, xx = x + dx;
        if (yy >= 0 && yy < HM_H && xx >= 0 && xx < HM_W)
          m = fmaxf(m, ws_hm[yy * HM_W + xx]);
      }
    v = (c == m) ? c : 0.f;
    idx = p;
  }
  sv[t * 4] = v; si[t * 4] = idx;
  #pragma unroll
  for (int k = 1; k < 4; ++k) { sv[t * 4 + k] = -1.f; si[t * 4 + k] = INT_MAX; }
  __syncthreads();
  top4_tree<256>(sv, si, t);
  if (t == 0) {
    #pragma unroll
    for (int k = 0; k < 4; ++k) { candv[b * 4 + k] = sv[k]; candi[b * 4 + k] = si[k]; }
  }
}

// ------------------------------------------------------------------
// K3: redundant final top-k merge + gen_params. Block i -> instance i.
// ------------------------------------------------------------------
__global__ void k_gen(const float* __restrict__ candv, const int* __restrict__ candi,
                      const float* __restrict__ out1, const float* __restrict__ params_w,
                      const float* __restrict__ params_b, float* __restrict__ ws_gp,
                      float* __restrict__ d_out) {
  __shared__ float sv[128 * 4];
  __shared__ int   si[128 * 4];
  __shared__ float col[C_IN];
  int t = threadIdx.x, i = blockIdx.x;
  if (t < 128) {
    #pragma unroll
    for (int k = 0; k < 4; ++k) { sv[t * 4 + k] = candv[t * 4 + k]; si[t * 4 + k] = candi[t * 4 + k]; }
  }
  __syncthreads();
  top4_tree<128>(sv, si, t);
  if (i == 0 && t < 4) {
    d_out[t]     = sv[t];
    d_out[4 + t] = (float)si[t];
  }
  int p = si[i];
  col[t] = out1[t * HM_N + p];
  __syncthreads();
  if (t < NP) {
    float s = params_b[t];
    #pragma unroll 8
    for (int c = 0; c < C_IN; ++c) s += params_w[t * C_IN + c] * col[c];
    ws_gp[i * NP + t] = s;
  }
}

// ------------------------------------------------------------------
// K4 v7: 2 blocks/CU. Block = 512 thr (8 waves), tile 8 rows x 32 px;
//   wave = 1 row (32 px) x 64 ch, acc[2][4].
//   - waves 0-6 (thr<400): A-staging, single 400-unit batch (dq=32 VGPR),
//     issued at P0(g), stored at P0(g+1) -> 3-phase flight, zero store stall
//   - wave 7: pure W-producer via global_load_lds, double-buffer, 1 ahead
//   - 3 phases/iter, raw barriers (lgkmcnt(0)+s_barrier, no vmcnt drain)
//   - XCD-chunked column-major swizzle (nwg=510: q=63, r=6)
// LDS: A 2x23040 + W 2x12288 = 70656 B -> 2 blocks/CU (141 KB), 4 waves/SIMD.
// ------------------------------------------------------------------
#define SR   10                 // stored rows (8 + 2 halo)
#define RP   36                 // stored x positions per row (gx0-1 .. gx0+34)
#define BUFU (SR * RP * 32)     // 11520 ushorts = 23040 B per A buffer
#define WOFF (2 * BUFU)         // ushort idx 23040; W bufs at byte 46080 + b*12288

#define PIPE_BARRIER() do {                                   \
    __builtin_amdgcn_sched_barrier(0);                        \
    asm volatile("s_waitcnt lgkmcnt(0)" ::: "memory");        \
    __builtin_amdgcn_s_barrier();                             \
    __builtin_amdgcn_sched_barrier(0);                        \
  } while (0)

// stage weight group G (3 taps = 12288B) into W buf (G&1); wave 7 only
#define STAGE_W(G)                                                        \
  if (wv == 7 && (G) < 24) {                                              \
    const char* wsrc = (const char*)wt + (G) * 12288 + lane * 16;         \
    char* wdst = (char*)smem + 46080 + ((G) & 1) * 12288;                 \
    _Pragma("unroll")                                                     \
    for (int i_ = 0; i_ < 12; ++i_)                                       \
      glds16(wsrc + i_ * 1024, wdst + i_ * 1024);                         \
  }

#define MFMA16(A, B, C) __builtin_amdgcn_mfma_f32_16x16x32_bf16(A, B, C, 0, 0, 0)

#define TAPS3(P) {                                                        \
    const unsigned short* wl = smem + WOFF + (((3 * g + (P)) & 1) * 6144) \
                               + lane * 8;                                \
    _Pragma("unroll")                                                     \
    for (int tt = 0; tt < 3; ++tt) {                                      \
      bf16x8 bb0 = *(const bf16x8*)(wl + tt * 2048);                      \
      bf16x8 bb1 = *(const bf16x8*)(wl + tt * 2048 + 512);                \
      bf16x8 bb2 = *(const bf16x8*)(wl + tt * 2048 + 1024);               \
      bf16x8 bb3 = *(const bf16x8*)(wl + tt * 2048 + 1536);               \
      const unsigned short* c0 = cur + lrdp[(P) * 3 + tt];                \
      bf16x8 a0 = *(const bf16x8*)c0;                                     \
      bf16x8 a1 = *(const bf16x8*)(c0 + 512);                             \
      acc[0][0] = MFMA16(a0, bb0, acc[0][0]);                             \
      acc[0][1] = MFMA16(a0, bb1, acc[0][1]);                             \
      acc[0][2] = MFMA16(a0, bb2, acc[0][2]);                             \
      acc[0][3] = MFMA16(a0, bb3, acc[0][3]);                             \
      acc[1][0] = MFMA16(a1, bb0, acc[1][0]);                             \
      acc[1][1] = MFMA16(a1, bb1, acc[1][1]);                             \
      acc[1][2] = MFMA16(a1, bb2, acc[1][2]);                             \
      acc[1][3] = MFMA16(a1, bb3, acc[1][3]);                             \
    } }

__device__ __forceinline__ void stage_store8(unsigned short* buf, const f32x4* dq,
                                             bool gv, const int* lw, unsigned sm) {
  #pragma unroll
  for (int e = 0; e < 4; ++e) if ((sm >> e) & 1u) {
    u16x8 v;
    #pragma unroll
    for (int j = 0; j < 8; ++j) v[j] = f2bf(gv ? dq[j][e] : 0.f);
    *(u16x8*)(buf + lw[e]) = v;
  }
}

__global__ __launch_bounds__(512, 4) void k_conv_mfma(
    const float* __restrict__ out0, const unsigned short* __restrict__ wt,
    const float* __restrict__ mb_b, const float* __restrict__ ws_gp,
    float* __restrict__ d_out) {
  __shared__ unsigned short smem[2 * BUFU + 2 * 6144];   // 70656 B

  int tid  = threadIdx.x;
  int lane = tid & 63;
  int wv   = tid >> 6;       // wave 0..7
  int n15  = lane & 15;
  int kq   = lane >> 4;

  // --- XCD-chunked bijective swizzle (nwg=510: q=63, r=6), column-major ---
  int orig = blockIdx.x;
  int xcd  = orig & 7, pos = orig >> 3;
  int wgid = (xcd < 6) ? (xcd * 64 + pos) : (384 + (xcd - 6) * 63 + pos);
  int bx = wgid / 34, by = wgid - bx * 34;
  int gx0 = bx * 32, gy0 = by * 8;

  // --- A staging: 400 units (co8[4] x row[10] x qx[10]); thread t<400 -> unit t
  bool ustage = tid < 400;
  int u    = ustage ? tid : 0;
  int co8  = u / 100;                 // 0..3
  int rem  = u - co8 * 100;
  int row  = rem / 10;                // 0..9
  int qx   = rem - row * 10;          // 0..9
  int iy   = gy0 + row - 1;
  int ixq  = gx0 + 4 * qx - 4;        // 16B-aligned quad
  bool gvld = ustage && (iy >= 0) && (iy < MH) && (ixq >= 0) && (ixq + 3 < MW);
  int goff  = gvld ? (co8 * 8 * MN + iy * MW + ixq) : 0;
  int lws[4]; unsigned smask = 0;
  #pragma unroll
  for (int e = 0; e < 4; ++e) {
    int sx = 4 * qx - 3 + e;          // stored x index
    bool sv = ustage && (sx >= 0) && (sx < RP);
    int pixw = row * RP + (sv ? sx : 0);
    int w2 = (pixw ^ (pixw >> 2)) & 3;
    int q  = (pixw ^ row) & 1;
    lws[e] = (pixw >> 1) * 64 + ((co8 ^ w2) << 4) + q * 8;
    if (sv) smask |= (1u << e);
  }

  // --- A-frag LDS read offsets per tap (subtile 1 = +512, +16 px) ---
  unsigned lrdp[9];
  #pragma unroll
  for (int t = 0; t < 9; ++t) {
    int ty = t / 3, tx = t - ty * 3;
    int sr = wv + ty;                 // stored row (wave wv owns tile row wv)
    int pix = sr * RP + n15 + tx;
    int w2 = (pix ^ (pix >> 2)) & 3;
    int q  = (pix ^ sr) & 1;
    lrdp[t] = (pix >> 1) * 64 + ((kq ^ w2) << 4) + q * 8;
  }

  // --- prologue: stage tile0 into buf0; issue tile1; stage W group 0 ---
  f32x4 dq[8];
  if (ustage) {
    const float* sp = out0 + goff;
    #pragma unroll
    for (int j = 0; j < 8; ++j) dq[j] = *(const f32x4*)(sp + j * MN);
  }
  stage_store8(smem, dq, gvld, lws, smask);   // waits only tile0 loads
  __builtin_amdgcn_sched_barrier(0);
  if (ustage) {
    const float* sp = out0 + 32 * MN + goff;  // tile1
    #pragma unroll
    for (int j = 0; j < 8; ++j) dq[j] = *(const f32x4*)(sp + j * MN);
  }
  __builtin_amdgcn_sched_barrier(0);
  STAGE_W(0);
  if (wv == 7) asm volatile("s_waitcnt vmcnt(0)" ::: "memory");
  PIPE_BARRIER();

  f32x4 acc[2][4];
  #pragma unroll
  for (int i = 0; i < 2; ++i)
    #pragma unroll
    for (int nt = 0; nt < 4; ++nt)
      acc[i][nt] = (f32x4){0.f, 0.f, 0.f, 0.f};

  #pragma unroll 1
  for (int g = 0; g < 8; ++g) {
    const unsigned short* cur = smem + (g & 1) * BUFU;
    unsigned short*       nxt = smem + ((g + 1) & 1) * BUFU;

    // ---- phase 0: store tile(g+1) [3 phases in flight] | issue tile(g+2)
    //               | W grp 3g+1 | taps 0-2 (grp 3g)
    STAGE_W(3 * g + 1);
    if (g < 7) stage_store8(nxt, dq, gvld, lws, smask);
    __builtin_amdgcn_sched_barrier(0);
    if (g < 6 && ustage) {
      const float* sp = out0 + (g + 2) * (32 * MN) + goff;
      #pragma unroll
      for (int j = 0; j < 8; ++j) dq[j] = *(const f32x4*)(sp + j * MN);
    }
    __builtin_amdgcn_sched_barrier(0);
    TAPS3(0)
    if (wv == 7) asm volatile("s_waitcnt vmcnt(0)" ::: "memory");
    PIPE_BARRIER();

    // ---- phase 1: W grp 3g+2 | taps 3-5 (grp 3g+1)
    STAGE_W(3 * g + 2);
    TAPS3(1)
    if (wv == 7) asm volatile("s_waitcnt vmcnt(0)" ::: "memory");
    PIPE_BARRIER();

    // ---- phase 2: W grp 3g+3 | taps 6-8 (grp 3g+2)
    STAGE_W(3 * g + 3);
    TAPS3(2)
    if (wv == 7) asm volatile("s_waitcnt vmcnt(0)" ::: "memory");
    PIPE_BARRIER();
  }

  // --- epilogue: bias+relu, acc -> LDS [pixel][channel] bf16 (256 x 66) ---
  #define ES 66
  {
    float bias[4];
    #pragma unroll
    for (int nt = 0; nt < 4; ++nt) bias[nt] = mb_b[nt * 16 + n15];
    #pragma unroll
    for (int i = 0; i < 2; ++i) {
      int pbase = wv * 32 + i * 16;
      #pragma unroll
      for (int nt = 0; nt < 4; ++nt)
        #pragma unroll
        for (int reg = 0; reg < 4; ++reg) {
          float vv = fmaxf(acc[i][nt][reg] + bias[nt], 0.f);
          smem[(pbase + kq * 4 + reg) * ES + nt * 16 + n15] = f2bf(vv);
        }
    }
  }
  __syncthreads();

  // dynamic heads: thread (p, half) -> pixel p (0..255), ch-half
  int p = tid & 255, hh = tid >> 8;
  int ob = hh * 32;
  float mres[4] = {0.f, 0.f, 0.f, 0.f};
  float rres[4] = {0.f, 0.f, 0.f, 0.f};
  #pragma unroll 8
  for (int o = 0; o < 32; ++o) {
    float v = b2f(smem[p * ES + ob + o]);
    #pragma unroll
    for (int i = 0; i < 4; ++i) {
      mres[i] += ws_gp[i * NP + ob + o] * v;
      rres[i] += ws_gp[i * NP + 67 + ob + o] * v;
    }
  }
  float* pf = (float*)smem + 8704;   // byte 34816, past 256x66 table (33792 B)
  if (hh) {
    #pragma unroll
    for (int i = 0; i < 4; ++i) { pf[p * 8 + i] = mres[i]; pf[p * 8 + 4 + i] = rres[i]; }
  }
  __syncthreads();
  if (!hh) {
    int r = p >> 5, xcol = p & 31;
    int gy = gy0 + r, gx = gx0 + xcol;
    float xc = -1.f + (2.f / 479.f) * (float)gx;
    float yc = -1.f + (2.f / 271.f) * (float)gy;
    int pix = gy * MW + gx;
    #pragma unroll
    for (int i = 0; i < 4; ++i) {
      const float* gp = ws_gp + i * NP;
      d_out[MASK_OFF + i * MN + pix] = mres[i] + pf[p * 8 + i]     + gp[66]  + gp[64]  * xc + gp[65]  * yc;
      d_out[REG_OFF  + i * MN + pix] = rres[i] + pf[p * 8 + 4 + i] + gp[133] + gp[131] * xc + gp[132] * yc;
    }
  }
}

// ------------------------------------------------------------------
// K5: feat_range MLP v2 — column staged in LDS by 64 parallel lanes
// (kills the 272-deep serial broadcast-load chain).
// ------------------------------------------------------------------
__global__ void k_mlp(const float* __restrict__ masks0, const float* __restrict__ w1,
                      const float* __restrict__ b1, const float* __restrict__ w2,
                      const float* __restrict__ b2, float* __restrict__ d_out) {
  __shared__ float ms[MH];
  int blk = blockIdx.x;          // i*480 + w
  int i = blk / MW;
  int w = blk - i * MW;
  int k = threadIdx.x;           // 0..63
  const float* mcol = masks0 + i * MN + w;
  for (int h = k; h < MH; h += 64) ms[h] = mcol[h * MW];
  __syncthreads();
  float s = b1[k];
  #pragma unroll 8
  for (int h = 0; h < MH; ++h) s += ms[h] * w1[h * HID + k];
  s = fmaxf(s, 0.f);
  float o0 = s * w2[k * 2 + 0];
  float o1 = s * w2[k * 2 + 1];
  #pragma unroll
  for (int off = 32; off >= 1; off >>= 1) {
    o0 += __shfl_down(o0, off);
    o1 += __shfl_down(o1, off);
  }
  if (k == 0) {
    d_out[FEAT_OFF + blk * 2 + 0] = o0 + b2[0];
    d_out[FEAT_OFF + blk * 2 + 1] = o1 + b2[1];
  }
}

// ------------------------------------------------------------------
extern "C" void kernel_launch(void* const* d_in, const int* in_sizes, int n_in,
                              void* d_out, int out_size, void* d_ws, size_t ws_size,
                              hipStream_t stream) {
  const float* out0     = (const float*)d_in[0];
  const float* out1     = (const float*)d_in[1];
  const float* hm_w     = (const float*)d_in[2];
  const float* hm_b     = (const float*)d_in[3];
  const float* params_w = (const float*)d_in[4];
  const float* params_b = (const float*)d_in[5];
  const float* mb_w     = (const float*)d_in[6];
  const float* mb_b     = (const float*)d_in[7];
  const float* mlp_w1   = (const float*)d_in[8];
  const float* mlp_b1   = (const float*)d_in[9];
  const float* mlp_w2   = (const float*)d_in[10];
  const float* mlp_b2   = (const float*)d_in[11];

  float* ws      = (float*)d_ws;
  float* ws_hm   = ws + WS_HM;
  float* candv   = ws + WS_CV;
  int*   candi   = (int*)(ws + WS_CI);
  float* ws_gp   = ws + WS_GP;
  unsigned short* ws_wt = (unsigned short*)(ws + WS_WT_F);
  float* out     = (float*)d_out;

  k_prep<<<1086, 256, 0, stream>>>(mb_w, ws_wt, out1, hm_w, hm_b, ws_hm);
  k_nms_top<<<128, 256, 0, stream>>>(ws_hm, candv, candi);
  k_gen<<<NI, 256, 0, stream>>>(candv, candi, out1, params_w, params_b, ws_gp, out);
  k_conv_mfma<<<510, 512, 0, stream>>>(out0, ws_wt, mb_b, ws_gp, out);
  k_mlp<<<NI * MW, 64, 0, stream>>>(out + MASK_OFF, mlp_w1, mlp_b1, mlp_w2, mlp_b2, out);
}

// Round 8
// 297.695 us; speedup vs baseline: 1.0733x; 1.0733x over previous
//
#include <hip/hip_runtime.h>
#include <math.h>
#include <limits.h>

// ---- problem constants ----
#define C_IN 256
#define HM_H 136
#define HM_W 240
#define HM_N (HM_H * HM_W)      // 32640
#define MB   64
#define MH   272
#define MW   480
#define MN   (MH * MW)          // 130560
#define NP   134
#define NI   4
#define HID  64

// d_out layout (floats): scores[4] | inds[4] | regs0[4*MN] | masks0[4*MN] | feat[4*480*2]
#define REG_OFF   8
#define MASK_OFF  (8 + NI * MN)
#define FEAT_OFF  (8 + 2 * NI * MN)

// ws layout (floats): hm[32640] | cand_v[512]+cand_i[512] | gp[536] | wt @ 65824
#define WS_HM   0
#define WS_CV   HM_N
#define WS_CI   (HM_N + 512)
#define WS_GP   (2 * HM_N)
#define WS_WT_F 65824

typedef float  f32x4  __attribute__((ext_vector_type(4)));
typedef short  bf16x8 __attribute__((ext_vector_type(8)));
typedef unsigned short u16x8 __attribute__((ext_vector_type(8)));

__device__ __forceinline__ unsigned short f2bf(float f) {
  unsigned int u = __float_as_uint(f);
  u += 0x7FFFu + ((u >> 16) & 1u);
  return (unsigned short)(u >> 16);
}
__device__ __forceinline__ float b2f(unsigned short h) {
  return __uint_as_float(((unsigned int)h) << 16);
}

__device__ __forceinline__ void glds16(const void* g, void* l) {
  __builtin_amdgcn_global_load_lds(
      (const __attribute__((address_space(1))) unsigned int*)g,
      (__attribute__((address_space(3))) unsigned int*)l, 16, 0, 0);
}

// ------------------------------------------------------------------
// K0: merged weight-prep + heatmap.
// ------------------------------------------------------------------
__global__ void k_prep(const float* __restrict__ mb_w, unsigned short* __restrict__ wt,
                       const float* __restrict__ out1, const float* __restrict__ hm_w,
                       const float* __restrict__ hm_b, float* __restrict__ ws_hm) {
  __shared__ float part[4][64];
  if (blockIdx.x < 576) {
    int idx = blockIdx.x * 256 + threadIdx.x;     // 147456 total
    int j    = idx & 7;
    int lane = (idx >> 3) & 63;
    int nt   = (idx >> 9) & 3;
    int gt   = idx >> 11;
    int t    = gt % 9;
    int g    = gt / 9;
    int n = nt * 16 + (lane & 15);
    int c = g * 32 + (lane >> 4) * 8 + j;
    wt[idx] = f2bf(mb_w[(n * C_IN + c) * 9 + t]);
  } else {
    int b = blockIdx.x - 576, t = threadIdx.x;
    int cg = t >> 6, pl = t & 63;
    int p = b * 64 + pl;                         // 510*64 = 32640
    float s = 0.f;
    #pragma unroll 16
    for (int c = 0; c < 64; ++c)
      s += hm_w[cg * 64 + c] * out1[(cg * 64 + c) * HM_N + p];
    part[cg][pl] = s;
    __syncthreads();
    if (t < 64) {
      float tot = part[0][t] + part[1][t] + part[2][t] + part[3][t] + hm_b[0];
      float sig = 1.f / (1.f + expf(-tot));
      sig = fminf(fmaxf(sig, 1e-4f), 1.f - 1e-4f);
      ws_hm[b * 64 + t] = sig;
    }
  }
}

// ------------------------------------------------------------------
// top-4 list merge helpers
// ------------------------------------------------------------------
__device__ __forceinline__ bool better(float av, int ai, float bv, int bi) {
  return (av > bv) || (av == bv && ai < bi);
}

template<int NTHR>
__device__ void top4_tree(float* sv, int* si, int t) {
  for (int s = NTHR / 2; s >= 1; s >>= 1) {
    if (t < s) {
      float a[4], b[4]; int ai[4], bj[4];
      #pragma unroll
      for (int k = 0; k < 4; ++k) {
        a[k] = sv[t * 4 + k];        ai[k] = si[t * 4 + k];
        b[k] = sv[(t + s) * 4 + k];  bj[k] = si[(t + s) * 4 + k];
      }
      float ov[4]; int oi[4];
      int i = 0, j = 0;
      #pragma unroll
      for (int k = 0; k < 4; ++k) {
        if (better(a[i], ai[i], b[j], bj[j])) { ov[k] = a[i]; oi[k] = ai[i]; ++i; }
        else                                   { ov[k] = b[j]; oi[k] = bj[j]; ++j; }
      }
      #pragma unroll
      for (int k = 0; k < 4; ++k) { sv[t * 4 + k] = ov[k]; si[t * 4 + k] = oi[k]; }
    }
    __syncthreads();
  }
}

// ------------------------------------------------------------------
// K2a: fused NMS + per-block top-4 (128 blocks x 255 pixels)
// ------------------------------------------------------------------
__global__ void k_nms_top(const float* __restrict__ ws_hm, float* __restrict__ candv,
                          int* __restrict__ candi) {
  __shared__ float sv[256 * 4];
  __shared__ int   si[256 * 4];
  int b = blockIdx.x, t = threadIdx.x;
  float v = -1.f; int idx = INT_MAX;
  if (t < 255) {
    int p = b * 255 + t;
    int y = p / HM_W, x = p - y * HM_W;
    float c = ws_hm[p], m = c;
    #pragma unroll
    for (int dy = -1; dy <= 1; ++dy)
      #pragma unroll
      for (int dx = -1; dx <= 1; ++dx) {
        int yy = y + dy, xx = x + dx;
        if (yy >= 0 && yy < HM_H && xx >= 0 && xx < HM_W)
          m = fmaxf(m, ws_hm[yy * HM_W + xx]);
      }
    v = (c == m) ? c : 0.f;
    idx = p;
  }
  sv[t * 4] = v; si[t * 4] = idx;
  #pragma unroll
  for (int k = 1; k < 4; ++k) { sv[t * 4 + k] = -1.f; si[t * 4 + k] = INT_MAX; }
  __syncthreads();
  top4_tree<256>(sv, si, t);
  if (t == 0) {
    #pragma unroll
    for (int k = 0; k < 4; ++k) { candv[b * 4 + k] = sv[k]; candi[b * 4 + k] = si[k]; }
  }
}

// ------------------------------------------------------------------
// K3: redundant final top-k merge + gen_params. Block i -> instance i.
// ------------------------------------------------------------------
__global__ void k_gen(const float* __restrict__ candv, const int* __restrict__ candi,
                      const float* __restrict__ out1, const float* __restrict__ params_w,
                      const float* __restrict__ params_b, float* __restrict__ ws_gp,
                      float* __restrict__ d_out) {
  __shared__ float sv[128 * 4];
  __shared__ int   si[128 * 4];
  __shared__ float col[C_IN];
  int t = threadIdx.x, i = blockIdx.x;
  if (t < 128) {
    #pragma unroll
    for (int k = 0; k < 4; ++k) { sv[t * 4 + k] = candv[t * 4 + k]; si[t * 4 + k] = candi[t * 4 + k]; }
  }
  __syncthreads();
  top4_tree<128>(sv, si, t);
  if (i == 0 && t < 4) {
    d_out[t]     = sv[t];
    d_out[4 + t] = (float)si[t];
  }
  int p = si[i];
  col[t] = out1[t * HM_N + p];
  __syncthreads();
  if (t < NP) {
    float s = params_b[t];
    #pragma unroll 8
    for (int c = 0; c < C_IN; ++c) s += params_w[t * C_IN + c] * col[c];
    ws_gp[i * NP + t] = s;
  }
}

// ------------------------------------------------------------------
// K4 v8: R5 structure (16-row tile, deep A-issue, XCD column swizzle)
//  with W staged as FULL 9-tap groups (36864B x 2 buffers) ->
//  ONE barrier per K-group instead of three (25 barriers -> 9).
// LDS: A 2x41472 + W 2x36864 = 156672 B (fits 160K) -> 1 block/CU.
// ------------------------------------------------------------------
#define SR   18                 // stored rows (16 + 2 halo)
#define RP   36                 // stored x positions per row
#define BUFU (SR * RP * 32)     // 20736 ushorts = 41472 B per A buffer
#define WBASE (2 * BUFU)        // ushort idx 41472 (byte 82944)
#define WBUFU 18432             // ushorts per W buffer (36864 B = 9 taps)

#define PIPE_BARRIER() do {                                   \
    __builtin_amdgcn_sched_barrier(0);                        \
    asm volatile("s_waitcnt lgkmcnt(0)" ::: "memory");        \
    __builtin_amdgcn_s_barrier();                             \
    __builtin_amdgcn_sched_barrier(0);                        \
  } while (0)

// stage ALL 9 taps of weight group G (36864B) into W buf (G&1); wave 7 only
#define STAGE_W_ALL(G)                                                    \
  if (wv == 7 && (G) < 8) {                                               \
    const char* wsrc = (const char*)wt + (G) * 36864 + lane * 16;         \
    char* wdst = (char*)smem + 82944 + ((G) & 1) * 36864;                 \
    _Pragma("unroll")                                                     \
    for (int i_ = 0; i_ < 36; ++i_)                                       \
      glds16(wsrc + i_ * 1024, wdst + i_ * 1024);                         \
  }

#define MFMA16(A, B, C) __builtin_amdgcn_mfma_f32_16x16x32_bf16(A, B, C, 0, 0, 0)

#define TAPS3(P) {                                                        \
    const unsigned short* wl = smem + WBASE + ((g) & 1) * WBUFU           \
                               + (P) * 6144 + lane * 8;                   \
    _Pragma("unroll")                                                     \
    for (int tt = 0; tt < 3; ++tt) {                                      \
      bf16x8 bb0 = *(const bf16x8*)(wl + tt * 2048);                      \
      bf16x8 bb1 = *(const bf16x8*)(wl + tt * 2048 + 512);                \
      bf16x8 bb2 = *(const bf16x8*)(wl + tt * 2048 + 1024);               \
      bf16x8 bb3 = *(const bf16x8*)(wl + tt * 2048 + 1536);               \
      unsigned pk = lrdp[(P) * 3 + tt];                                   \
      const unsigned short* c0 = cur + (pk & 0xFFFFu);                    \
      const unsigned short* c1 = cur + (pk >> 16);                        \
      bf16x8 a0 = *(const bf16x8*)c0;                                     \
      bf16x8 a1 = *(const bf16x8*)(c0 + 512);                             \
      bf16x8 a2 = *(const bf16x8*)c1;                                     \
      bf16x8 a3 = *(const bf16x8*)(c1 + 512);                             \
      acc[0][0] = MFMA16(a0, bb0, acc[0][0]);                             \
      acc[0][1] = MFMA16(a0, bb1, acc[0][1]);                             \
      acc[0][2] = MFMA16(a0, bb2, acc[0][2]);                             \
      acc[0][3] = MFMA16(a0, bb3, acc[0][3]);                             \
      acc[1][0] = MFMA16(a1, bb0, acc[1][0]);                             \
      acc[1][1] = MFMA16(a1, bb1, acc[1][1]);                             \
      acc[1][2] = MFMA16(a1, bb2, acc[1][2]);                             \
      acc[1][3] = MFMA16(a1, bb3, acc[1][3]);                             \
      acc[2][0] = MFMA16(a2, bb0, acc[2][0]);                             \
      acc[2][1] = MFMA16(a2, bb1, acc[2][1]);                             \
      acc[2][2] = MFMA16(a2, bb2, acc[2][2]);                             \
      acc[2][3] = MFMA16(a2, bb3, acc[2][3]);                             \
      acc[3][0] = MFMA16(a3, bb0, acc[3][0]);                             \
      acc[3][1] = MFMA16(a3, bb1, acc[3][1]);                             \
      acc[3][2] = MFMA16(a3, bb2, acc[3][2]);                             \
      acc[3][3] = MFMA16(a3, bb3, acc[3][3]);                             \
    } }

__device__ __forceinline__ void stage_store8(unsigned short* buf, const f32x4* dq,
                                             bool gv, const int* lw, unsigned sm) {
  #pragma unroll
  for (int e = 0; e < 4; ++e) if ((sm >> e) & 1u) {
    u16x8 v;
    #pragma unroll
    for (int j = 0; j < 8; ++j) v[j] = f2bf(gv ? dq[j][e] : 0.f);
    *(u16x8*)(buf + lw[e]) = v;
  }
}

__global__ __launch_bounds__(512, 2) void k_conv_mfma(
    const float* __restrict__ out0, const unsigned short* __restrict__ wt,
    const float* __restrict__ mb_b, const float* __restrict__ ws_gp,
    float* __restrict__ d_out) {
  __shared__ unsigned short smem[2 * BUFU + 2 * WBUFU];   // 156672 B

  int tid  = threadIdx.x;
  int lane = tid & 63;
  int wv   = tid >> 6;       // wave 0..7
  int n15  = lane & 15;
  int kq   = lane >> 4;

  // --- XCD-chunked bijective swizzle (nwg=255: q=31, r=7), column-major ---
  int orig = blockIdx.x;
  int xcd  = orig & 7, pos = orig >> 3;
  int wgid = (xcd < 7) ? (xcd * 32 + pos) : (224 + pos);
  int bx = wgid / 17, by = wgid - bx * 17;
  int gx0 = bx * 32, gy0 = by * 16;

  // --- A staging: 720 units; thread t<360 handles unit t (co8 0..1) & t+360 (co8 2..3)
  bool ustage = tid < 360;
  int u    = ustage ? tid : 0;
  int co8  = u / 180;                 // 0..1
  int rem  = u - co8 * 180;
  int row  = rem / 10;                // 0..17
  int qx   = rem - row * 10;          // 0..9
  int iy   = gy0 + row - 1;
  int ixq  = gx0 + 4 * qx - 4;        // 16B-aligned quad
  bool gvld = ustage && (iy >= 0) && (iy < MH) && (ixq >= 0) && (ixq + 3 < MW);
  int goffA = gvld ? (co8 * 8 * MN + iy * MW + ixq) : 0;
  int lwsA[4]; unsigned smask = 0;
  #pragma unroll
  for (int e = 0; e < 4; ++e) {
    int sx = 4 * qx - 3 + e;          // stored x index
    bool sv = ustage && (sx >= 0) && (sx < RP);
    int pixw = row * RP + (sv ? sx : 0);
    int w2 = (pixw ^ (pixw >> 2)) & 3;
    int q  = (pixw ^ row) & 1;
    lwsA[e] = (pixw >> 1) * 64 + ((co8 ^ w2) << 4) + q * 8;
    if (sv) smask |= (1u << e);
  }
  // sub-stage B: lwsB[e] = lwsA[e] ^ 32, goffB = goffA + 16*MN

  // --- A-frag LDS read offsets: packed (o_row0 | o_row1<<16); +512 = x-half ---
  unsigned lrdp[9];
  #pragma unroll
  for (int t = 0; t < 9; ++t) {
    int ty = t / 3, tx = t - ty * 3;
    int sr0 = 2 * wv + ty;            // stored row for subtiles 0,1
    int pix0 = sr0 * RP + n15 + tx;
    int w20 = (pix0 ^ (pix0 >> 2)) & 3;
    int q0  = (pix0 ^ sr0) & 1;
    unsigned o0 = (pix0 >> 1) * 64 + ((kq ^ w20) << 4) + q0 * 8;
    int sr1 = sr0 + 1;                // subtiles 2,3
    int pix1 = sr1 * RP + n15 + tx;
    int w21 = (pix1 ^ (pix1 >> 2)) & 3;
    int q1  = (pix1 ^ sr1) & 1;
    unsigned o1 = (pix1 >> 1) * 64 + ((kq ^ w21) << 4) + q1 * 8;
    lrdp[t] = o0 | (o1 << 16);
  }

  // --- prologue: stage tile0 into buf0; issue tile1; stage W group 0 ---
  f32x4 dqA[8], dqB[8];
  if (ustage) {
    const float* sp = out0 + goffA;
    #pragma unroll
    for (int j = 0; j < 8; ++j) dqA[j] = *(const f32x4*)(sp + j * MN);
  }
  stage_store8(smem, dqA, gvld, lwsA, smask);
  if (ustage) {
    const float* sp = out0 + goffA + 16 * MN;
    #pragma unroll
    for (int j = 0; j < 8; ++j) dqB[j] = *(const f32x4*)(sp + j * MN);
  }
  {
    int lwsB[4];
    #pragma unroll
    for (int e = 0; e < 4; ++e) lwsB[e] = lwsA[e] ^ 32;
    stage_store8(smem, dqB, gvld, lwsB, smask);
  }
  __builtin_amdgcn_sched_barrier(0);
  if (ustage) {
    const float* sp = out0 + 32 * MN + goffA;           // tile1 subA
    #pragma unroll
    for (int j = 0; j < 8; ++j) dqA[j] = *(const f32x4*)(sp + j * MN);
    const float* sq = out0 + 32 * MN + goffA + 16 * MN; // tile1 subB
    #pragma unroll
    for (int j = 0; j < 8; ++j) dqB[j] = *(const f32x4*)(sq + j * MN);
  }
  __builtin_amdgcn_sched_barrier(0);
  STAGE_W_ALL(0);
  if (wv == 7) asm volatile("s_waitcnt vmcnt(0)" ::: "memory");
  PIPE_BARRIER();

  f32x4 acc[4][4];
  #pragma unroll
  for (int i = 0; i < 4; ++i)
    #pragma unroll
    for (int nt = 0; nt < 4; ++nt)
      acc[i][nt] = (f32x4){0.f, 0.f, 0.f, 0.f};

  #pragma unroll 1
  for (int g = 0; g < 8; ++g) {
    const unsigned short* cur = smem + (g & 1) * BUFU;
    unsigned short*       nxt = smem + ((g + 1) & 1) * BUFU;

    // issue next W group early (wave 7; consumed after this iteration's barrier)
    STAGE_W_ALL(g + 1);
    // store tile(g+1) [loads issued a full iteration ago -> landed]
    if (g < 7) {
      stage_store8(nxt, dqA, gvld, lwsA, smask);
      int lwsB[4];
      #pragma unroll
      for (int e = 0; e < 4; ++e) lwsB[e] = lwsA[e] ^ 32;
      stage_store8(nxt, dqB, gvld, lwsB, smask);
    }
    __builtin_amdgcn_sched_barrier(0);
    // issue tile(g+2)
    if (g < 6 && ustage) {
      const float* sp = out0 + (g + 2) * (32 * MN) + goffA;
      #pragma unroll
      for (int j = 0; j < 8; ++j) dqA[j] = *(const f32x4*)(sp + j * MN);
      const float* sq = out0 + (g + 2) * (32 * MN) + goffA + 16 * MN;
      #pragma unroll
      for (int j = 0; j < 8; ++j) dqB[j] = *(const f32x4*)(sq + j * MN);
    }
    __builtin_amdgcn_sched_barrier(0);

    // all 9 taps, no intra-iteration barriers
    TAPS3(0)
    TAPS3(1)
    TAPS3(2)

    if (wv == 7) asm volatile("s_waitcnt vmcnt(0)" ::: "memory");
    PIPE_BARRIER();
  }

  // --- epilogue: bias+relu, acc -> LDS [pixel][channel] bf16 (512 x 66) ---
  #define ES 66
  {
    float bias[4];
    #pragma unroll
    for (int nt = 0; nt < 4; ++nt) bias[nt] = mb_b[nt * 16 + n15];
    #pragma unroll
    for (int i = 0; i < 4; ++i) {
      int pbase = (2 * wv + (i >> 1)) * 32 + (i & 1) * 16;
      #pragma unroll
      for (int nt = 0; nt < 4; ++nt)
        #pragma unroll
        for (int reg = 0; reg < 4; ++reg) {
          float vv = fmaxf(acc[i][nt][reg] + bias[nt], 0.f);
          smem[(pbase + kq * 4 + reg) * ES + nt * 16 + n15] = f2bf(vv);
        }
    }
  }
  __syncthreads();

  // dynamic heads: 2 passes of 256 px; thread (p, half) -> pixel, ch-half
  int p = tid & 255, hh = tid >> 8;
  int ob = hh * 32;
  float* pf = (float*)smem + 16896;   // byte 67584, past 512x66 table
  #pragma unroll 1
  for (int ps = 0; ps < 2; ++ps) {
    int pixel = ps * 256 + p;
    float mres[4] = {0.f, 0.f, 0.f, 0.f};
    float rres[4] = {0.f, 0.f, 0.f, 0.f};
    #pragma unroll 8
    for (int o = 0; o < 32; ++o) {
      float v = b2f(smem[pixel * ES + ob + o]);
      #pragma unroll
      for (int i = 0; i < 4; ++i) {
        mres[i] += ws_gp[i * NP + ob + o] * v;
        rres[i] += ws_gp[i * NP + 67 + ob + o] * v;
      }
    }
    if (hh) {
      #pragma unroll
      for (int i = 0; i < 4; ++i) { pf[p * 8 + i] = mres[i]; pf[p * 8 + 4 + i] = rres[i]; }
    }
    __syncthreads();
    if (!hh) {
      int r = pixel >> 5, xcol = pixel & 31;
      int gy = gy0 + r, gx = gx0 + xcol;
      float xc = -1.f + (2.f / 479.f) * (float)gx;
      float yc = -1.f + (2.f / 271.f) * (float)gy;
      int pix = gy * MW + gx;
      #pragma unroll
      for (int i = 0; i < 4; ++i) {
        const float* gp = ws_gp + i * NP;
        d_out[MASK_OFF + i * MN + pix] = mres[i] + pf[p * 8 + i]     + gp[66]  + gp[64]  * xc + gp[65]  * yc;
        d_out[REG_OFF  + i * MN + pix] = rres[i] + pf[p * 8 + 4 + i] + gp[133] + gp[131] * xc + gp[132] * yc;
      }
    }
    __syncthreads();
  }
}

// ------------------------------------------------------------------
// K5: feat_range MLP — column staged in LDS by 64 parallel lanes
// ------------------------------------------------------------------
__global__ void k_mlp(const float* __restrict__ masks0, const float* __restrict__ w1,
                      const float* __restrict__ b1, const float* __restrict__ w2,
                      const float* __restrict__ b2, float* __restrict__ d_out) {
  __shared__ float ms[MH];
  int blk = blockIdx.x;          // i*480 + w
  int i = blk / MW;
  int w = blk - i * MW;
  int k = threadIdx.x;           // 0..63
  const float* mcol = masks0 + i * MN + w;
  for (int h = k; h < MH; h += 64) ms[h] = mcol[h * MW];
  __syncthreads();
  float s = b1[k];
  #pragma unroll 8
  for (int h = 0; h < MH; ++h) s += ms[h] * w1[h * HID + k];
  s = fmaxf(s, 0.f);
  float o0 = s * w2[k * 2 + 0];
  float o1 = s * w2[k * 2 + 1];
  #pragma unroll
  for (int off = 32; off >= 1; off >>= 1) {
    o0 += __shfl_down(o0, off);
    o1 += __shfl_down(o1, off);
  }
  if (k == 0) {
    d_out[FEAT_OFF + blk * 2 + 0] = o0 + b2[0];
    d_out[FEAT_OFF + blk * 2 + 1] = o1 + b2[1];
  }
}

// ------------------------------------------------------------------
extern "C" void kernel_launch(void* const* d_in, const int* in_sizes, int n_in,
                              void* d_out, int out_size, void* d_ws, size_t ws_size,
                              hipStream_t stream) {
  const float* out0     = (const float*)d_in[0];
  const float* out1     = (const float*)d_in[1];
  const float* hm_w     = (const float*)d_in[2];
  const float* hm_b     = (const float*)d_in[3];
  const float* params_w = (const float*)d_in[4];
  const float* params_b = (const float*)d_in[5];
  const float* mb_w     = (const float*)d_in[6];
  const float* mb_b     = (const float*)d_in[7];
  const float* mlp_w1   = (const float*)d_in[8];
  const float* mlp_b1   = (const float*)d_in[9];
  const float* mlp_w2   = (const float*)d_in[10];
  const float* mlp_b2   = (const float*)d_in[11];

  float* ws      = (float*)d_ws;
  float* ws_hm   = ws + WS_HM;
  float* candv   = ws + WS_CV;
  int*   candi   = (int*)(ws + WS_CI);
  float* ws_gp   = ws + WS_GP;
  unsigned short* ws_wt = (unsigned short*)(ws + WS_WT_F);
  float* out     = (float*)d_out;

  k_prep<<<1086, 256, 0, stream>>>(mb_w, ws_wt, out1, hm_w, hm_b, ws_hm);
  k_nms_top<<<128, 256, 0, stream>>>(ws_hm, candv, candi);
  k_gen<<<NI, 256, 0, stream>>>(candv, candi, out1, params_w, params_b, ws_gp, out);
  k_conv_mfma<<<255, 512, 0, stream>>>(out0, ws_wt, mb_b, ws_gp, out);
  k_mlp<<<NI * MW, 64, 0, stream>>>(out + MASK_OFF, mlp_w1, mlp_b1, mlp_w2, mlp_b2, out);
}

// Round 9
// 295.901 us; speedup vs baseline: 1.0798x; 1.0061x over previous
//
#include <hip/hip_runtime.h>
#include <math.h>
#include <limits.h>

// ---- problem constants ----
#define C_IN 256
#define HM_H 136
#define HM_W 240
#define HM_N (HM_H * HM_W)      // 32640
#define MB   64
#define MH   272
#define MW   480
#define MN   (MH * MW)          // 130560
#define NP   134
#define NI   4
#define HID  64

// d_out layout (floats): scores[4] | inds[4] | regs0[4*MN] | masks0[4*MN] | feat[4*480*2]
#define REG_OFF   8
#define MASK_OFF  (8 + NI * MN)
#define FEAT_OFF  (8 + 2 * NI * MN)

// ws layout (floats): hm[32640] | cand_v[512]+cand_i[512] | gp[536] | wt @ 65824
#define WS_HM   0
#define WS_CV   HM_N
#define WS_CI   (HM_N + 512)
#define WS_GP   (2 * HM_N)
#define WS_WT_F 65824

typedef float  f32x4  __attribute__((ext_vector_type(4)));
typedef short  bf16x8 __attribute__((ext_vector_type(8)));
typedef unsigned int u32x4 __attribute__((ext_vector_type(4)));

__device__ __forceinline__ unsigned short f2bf(float f) {
  unsigned int u = __float_as_uint(f);
  u += 0x7FFFu + ((u >> 16) & 1u);
  return (unsigned short)(u >> 16);
}
__device__ __forceinline__ float b2f(unsigned short h) {
  return __uint_as_float(((unsigned int)h) << 16);
}
// pack 2 f32 -> 2 bf16 (RNE) in one VALU op; lo=a, hi=b
__device__ __forceinline__ unsigned cvtpk(float a, float b) {
  unsigned r;
  asm("v_cvt_pk_bf16_f32 %0, %1, %2" : "=v"(r) : "v"(a), "v"(b));
  return r;
}

__device__ __forceinline__ void glds16(const void* g, void* l) {
  __builtin_amdgcn_global_load_lds(
      (const __attribute__((address_space(1))) unsigned int*)g,
      (__attribute__((address_space(3))) unsigned int*)l, 16, 0, 0);
}

// ------------------------------------------------------------------
// K0: merged weight-prep + heatmap.
// ------------------------------------------------------------------
__global__ void k_prep(const float* __restrict__ mb_w, unsigned short* __restrict__ wt,
                       const float* __restrict__ out1, const float* __restrict__ hm_w,
                       const float* __restrict__ hm_b, float* __restrict__ ws_hm) {
  __shared__ float part[4][64];
  if (blockIdx.x < 576) {
    int idx = blockIdx.x * 256 + threadIdx.x;     // 147456 total
    int j    = idx & 7;
    int lane = (idx >> 3) & 63;
    int nt   = (idx >> 9) & 3;
    int gt   = idx >> 11;
    int t    = gt % 9;
    int g    = gt / 9;
    int n = nt * 16 + (lane & 15);
    int c = g * 32 + (lane >> 4) * 8 + j;
    wt[idx] = f2bf(mb_w[(n * C_IN + c) * 9 + t]);
  } else {
    int b = blockIdx.x - 576, t = threadIdx.x;
    int cg = t >> 6, pl = t & 63;
    int p = b * 64 + pl;                         // 510*64 = 32640
    float s = 0.f;
    #pragma unroll 16
    for (int c = 0; c < 64; ++c)
      s += hm_w[cg * 64 + c] * out1[(cg * 64 + c) * HM_N + p];
    part[cg][pl] = s;
    __syncthreads();
    if (t < 64) {
      float tot = part[0][t] + part[1][t] + part[2][t] + part[3][t] + hm_b[0];
      float sig = 1.f / (1.f + expf(-tot));
      sig = fminf(fmaxf(sig, 1e-4f), 1.f - 1e-4f);
      ws_hm[b * 64 + t] = sig;
    }
  }
}

// ------------------------------------------------------------------
// top-4 list merge helpers
// ------------------------------------------------------------------
__device__ __forceinline__ bool better(float av, int ai, float bv, int bi) {
  return (av > bv) || (av == bv && ai < bi);
}

template<int NTHR>
__device__ void top4_tree(float* sv, int* si, int t) {
  for (int s = NTHR / 2; s >= 1; s >>= 1) {
    if (t < s) {
      float a[4], b[4]; int ai[4], bj[4];
      #pragma unroll
      for (int k = 0; k < 4; ++k) {
        a[k] = sv[t * 4 + k];        ai[k] = si[t * 4 + k];
        b[k] = sv[(t + s) * 4 + k];  bj[k] = si[(t + s) * 4 + k];
      }
      float ov[4]; int oi[4];
      int i = 0, j = 0;
      #pragma unroll
      for (int k = 0; k < 4; ++k) {
        if (better(a[i], ai[i], b[j], bj[j])) { ov[k] = a[i]; oi[k] = ai[i]; ++i; }
        else                                   { ov[k] = b[j]; oi[k] = bj[j]; ++j; }
      }
      #pragma unroll
      for (int k = 0; k < 4; ++k) { sv[t * 4 + k] = ov[k]; si[t * 4 + k] = oi[k]; }
    }
    __syncthreads();
  }
}

// ------------------------------------------------------------------
// K2a: fused NMS + per-block top-4 (128 blocks x 255 pixels)
// ------------------------------------------------------------------
__global__ void k_nms_top(const float* __restrict__ ws_hm, float* __restrict__ candv,
                          int* __restrict__ candi) {
  __shared__ float sv[256 * 4];
  __shared__ int   si[256 * 4];
  int b = blockIdx.x, t = threadIdx.x;
  float v = -1.f; int idx = INT_MAX;
  if (t < 255) {
    int p = b * 255 + t;
    int y = p / HM_W, x = p - y * HM_W;
    float c = ws_hm[p], m = c;
    #pragma unroll
    for (int dy = -1; dy <= 1; ++dy)
      #pragma unroll
      for (int dx = -1; dx <= 1; ++dx) {
        int yy = y + dy, xx = x + dx;
        if (yy >= 0 && yy < HM_H && xx >= 0 && xx < HM_W)
          m = fmaxf(m, ws_hm[yy * HM_W + xx]);
      }
    v = (c == m) ? c : 0.f;
    idx = p;
  }
  sv[t * 4] = v; si[t * 4] = idx;
  #pragma unroll
  for (int k = 1; k < 4; ++k) { sv[t * 4 + k] = -1.f; si[t * 4 + k] = INT_MAX; }
  __syncthreads();
  top4_tree<256>(sv, si, t);
  if (t == 0) {
    #pragma unroll
    for (int k = 0; k < 4; ++k) { candv[b * 4 + k] = sv[k]; candi[b * 4 + k] = si[k]; }
  }
}

// ------------------------------------------------------------------
// K3: redundant final top-k merge + gen_params. Block i -> instance i.
// v2: 512 threads, channel loop split in 2 halves + LDS combine.
// ------------------------------------------------------------------
__global__ void k_gen(const float* __restrict__ candv, const int* __restrict__ candi,
                      const float* __restrict__ out1, const float* __restrict__ params_w,
                      const float* __restrict__ params_b, float* __restrict__ ws_gp,
                      float* __restrict__ d_out) {
  __shared__ float sv[128 * 4];
  __shared__ int   si[128 * 4];
  __shared__ float col[C_IN];
  __shared__ float part[NP];
  int t = threadIdx.x, i = blockIdx.x;   // 512 threads
  if (t < 128) {
    #pragma unroll
    for (int k = 0; k < 4; ++k) { sv[t * 4 + k] = candv[t * 4 + k]; si[t * 4 + k] = candi[t * 4 + k]; }
  }
  __syncthreads();
  top4_tree<128>(sv, si, t);
  if (i == 0 && t < 4) {
    d_out[t]     = sv[t];
    d_out[4 + t] = (float)si[t];
  }
  int p = si[i];
  if (t < 256) col[t] = out1[t * HM_N + p];
  __syncthreads();
  int half = t >> 8, jj = t & 255;
  float s = 0.f;
  if (jj < NP) {
    s = half ? 0.f : params_b[jj];
    const float* pw = params_w + jj * C_IN + half * 128;
    const float* cl = col + half * 128;
    #pragma unroll 8
    for (int c = 0; c < 128; ++c) s += pw[c] * cl[c];
    if (half) part[jj] = s;
  }
  __syncthreads();
  if (!half && jj < NP) ws_gp[i * NP + jj] = s + part[jj];
}

// ------------------------------------------------------------------
// K4 v9: R8 structure (16-row tile, deep A-issue, XCD column swizzle,
//  full 9-tap W groups, 9 barriers) with VALU-lean staging:
//   - dq zero-initialized once; loads predicated on gvld (loop-invariant)
//     -> no per-element validity cndmask
//   - f32->bf16 via v_cvt_pk_bf16_f32 (1 VALU / 2 elements)
// LDS: A 2x41472 + W 2x36864 = 156672 B -> 1 block/CU.
// ------------------------------------------------------------------
#define SR   18                 // stored rows (16 + 2 halo)
#define RP   36                 // stored x positions per row
#define BUFU (SR * RP * 32)     // 20736 ushorts = 41472 B per A buffer
#define WBASE (2 * BUFU)        // ushort idx 41472 (byte 82944)
#define WBUFU 18432             // ushorts per W buffer (36864 B = 9 taps)

#define PIPE_BARRIER() do {                                   \
    __builtin_amdgcn_sched_barrier(0);                        \
    asm volatile("s_waitcnt lgkmcnt(0)" ::: "memory");        \
    __builtin_amdgcn_s_barrier();                             \
    __builtin_amdgcn_sched_barrier(0);                        \
  } while (0)

// stage ALL 9 taps of weight group G (36864B) into W buf (G&1); wave 7 only
#define STAGE_W_ALL(G)                                                    \
  if (wv == 7 && (G) < 8) {                                               \
    const char* wsrc = (const char*)wt + (G) * 36864 + lane * 16;         \
    char* wdst = (char*)smem + 82944 + ((G) & 1) * 36864;                 \
    _Pragma("unroll")                                                     \
    for (int i_ = 0; i_ < 36; ++i_)                                       \
      glds16(wsrc + i_ * 1024, wdst + i_ * 1024);                         \
  }

#define MFMA16(A, B, C) __builtin_amdgcn_mfma_f32_16x16x32_bf16(A, B, C, 0, 0, 0)

#define TAPS3(P) {                                                        \
    const unsigned short* wl = smem + WBASE + ((g) & 1) * WBUFU           \
                               + (P) * 6144 + lane * 8;                   \
    _Pragma("unroll")                                                     \
    for (int tt = 0; tt < 3; ++tt) {                                      \
      bf16x8 bb0 = *(const bf16x8*)(wl + tt * 2048);                      \
      bf16x8 bb1 = *(const bf16x8*)(wl + tt * 2048 + 512);                \
      bf16x8 bb2 = *(const bf16x8*)(wl + tt * 2048 + 1024);               \
      bf16x8 bb3 = *(const bf16x8*)(wl + tt * 2048 + 1536);               \
      unsigned pk = lrdp[(P) * 3 + tt];                                   \
      const unsigned short* c0 = cur + (pk & 0xFFFFu);                    \
      const unsigned short* c1 = cur + (pk >> 16);                        \
      bf16x8 a0 = *(const bf16x8*)c0;                                     \
      bf16x8 a1 = *(const bf16x8*)(c0 + 512);                             \
      bf16x8 a2 = *(const bf16x8*)c1;                                     \
      bf16x8 a3 = *(const bf16x8*)(c1 + 512);                             \
      acc[0][0] = MFMA16(a0, bb0, acc[0][0]);                             \
      acc[0][1] = MFMA16(a0, bb1, acc[0][1]);                             \
      acc[0][2] = MFMA16(a0, bb2, acc[0][2]);                             \
      acc[0][3] = MFMA16(a0, bb3, acc[0][3]);                             \
      acc[1][0] = MFMA16(a1, bb0, acc[1][0]);                             \
      acc[1][1] = MFMA16(a1, bb1, acc[1][1]);                             \
      acc[1][2] = MFMA16(a1, bb2, acc[1][2]);                             \
      acc[1][3] = MFMA16(a1, bb3, acc[1][3]);                             \
      acc[2][0] = MFMA16(a2, bb0, acc[2][0]);                             \
      acc[2][1] = MFMA16(a2, bb1, acc[2][1]);                             \
      acc[2][2] = MFMA16(a2, bb2, acc[2][2]);                             \
      acc[2][3] = MFMA16(a2, bb3, acc[2][3]);                             \
      acc[3][0] = MFMA16(a3, bb0, acc[3][0]);                             \
      acc[3][1] = MFMA16(a3, bb1, acc[3][1]);                             \
      acc[3][2] = MFMA16(a3, bb2, acc[3][2]);                             \
      acc[3][3] = MFMA16(a3, bb3, acc[3][3]);                             \
    } }

// stores: dq already holds zeros for invalid threads; no select needed.
__device__ __forceinline__ void stage_store8(unsigned short* buf, const f32x4* dq,
                                             const int* lw, unsigned sm) {
  #pragma unroll
  for (int e = 0; e < 4; ++e) if ((sm >> e) & 1u) {
    u32x4 v;
    v[0] = cvtpk(dq[0][e], dq[1][e]);
    v[1] = cvtpk(dq[2][e], dq[3][e]);
    v[2] = cvtpk(dq[4][e], dq[5][e]);
    v[3] = cvtpk(dq[6][e], dq[7][e]);
    *(u32x4*)(buf + lw[e]) = v;
  }
}

__global__ __launch_bounds__(512, 2) void k_conv_mfma(
    const float* __restrict__ out0, const unsigned short* __restrict__ wt,
    const float* __restrict__ mb_b, const float* __restrict__ ws_gp,
    float* __restrict__ d_out) {
  __shared__ unsigned short smem[2 * BUFU + 2 * WBUFU];   // 156672 B

  int tid  = threadIdx.x;
  int lane = tid & 63;
  int wv   = tid >> 6;       // wave 0..7
  int n15  = lane & 15;
  int kq   = lane >> 4;

  // --- XCD-chunked bijective swizzle (nwg=255: q=31, r=7), column-major ---
  int orig = blockIdx.x;
  int xcd  = orig & 7, pos = orig >> 3;
  int wgid = (xcd < 7) ? (xcd * 32 + pos) : (224 + pos);
  int bx = wgid / 17, by = wgid - bx * 17;
  int gx0 = bx * 32, gy0 = by * 16;

  // --- A staging: 720 units; thread t<360 handles unit t (co8 0..1) & t+360 (co8 2..3)
  bool ustage = tid < 360;
  int u    = ustage ? tid : 0;
  int co8  = u / 180;                 // 0..1
  int rem  = u - co8 * 180;
  int row  = rem / 10;                // 0..17
  int qx   = rem - row * 10;          // 0..9
  int iy   = gy0 + row - 1;
  int ixq  = gx0 + 4 * qx - 4;        // 16B-aligned quad
  bool gvld = ustage && (iy >= 0) && (iy < MH) && (ixq >= 0) && (ixq + 3 < MW);
  int goffA = gvld ? (co8 * 8 * MN + iy * MW + ixq) : 0;
  int lwsA[4]; unsigned smask = 0;
  #pragma unroll
  for (int e = 0; e < 4; ++e) {
    int sx = 4 * qx - 3 + e;          // stored x index
    bool sv = ustage && (sx >= 0) && (sx < RP);
    int pixw = row * RP + (sv ? sx : 0);
    int w2 = (pixw ^ (pixw >> 2)) & 3;
    int q  = (pixw ^ row) & 1;
    lwsA[e] = (pixw >> 1) * 64 + ((co8 ^ w2) << 4) + q * 8;
    if (sv) smask |= (1u << e);
  }
  // sub-stage B: lwsB[e] = lwsA[e] ^ 32, goffB = goffA + 16*MN

  // --- A-frag LDS read offsets: packed (o_row0 | o_row1<<16); +512 = x-half ---
  unsigned lrdp[9];
  #pragma unroll
  for (int t = 0; t < 9; ++t) {
    int ty = t / 3, tx = t - ty * 3;
    int sr0 = 2 * wv + ty;            // stored row for subtiles 0,1
    int pix0 = sr0 * RP + n15 + tx;
    int w20 = (pix0 ^ (pix0 >> 2)) & 3;
    int q0  = (pix0 ^ sr0) & 1;
    unsigned o0 = (pix0 >> 1) * 64 + ((kq ^ w20) << 4) + q0 * 8;
    int sr1 = sr0 + 1;                // subtiles 2,3
    int pix1 = sr1 * RP + n15 + tx;
    int w21 = (pix1 ^ (pix1 >> 2)) & 3;
    int q1  = (pix1 ^ sr1) & 1;
    unsigned o1 = (pix1 >> 1) * 64 + ((kq ^ w21) << 4) + q1 * 8;
    lrdp[t] = o0 | (o1 << 16);
  }

  // --- prologue: zero dq; stage tile0 into buf0; issue tile1; W group 0 ---
  f32x4 dqA[8], dqB[8];
  #pragma unroll
  for (int j = 0; j < 8; ++j) {
    dqA[j] = (f32x4){0.f, 0.f, 0.f, 0.f};
    dqB[j] = (f32x4){0.f, 0.f, 0.f, 0.f};
  }
  if (gvld) {
    const float* sp = out0 + goffA;
    #pragma unroll
    for (int j = 0; j < 8; ++j) dqA[j] = *(const f32x4*)(sp + j * MN);
  }
  stage_store8(smem, dqA, lwsA, smask);
  if (gvld) {
    const float* sp = out0 + goffA + 16 * MN;
    #pragma unroll
    for (int j = 0; j < 8; ++j) dqB[j] = *(const f32x4*)(sp + j * MN);
  }
  {
    int lwsB[4];
    #pragma unroll
    for (int e = 0; e < 4; ++e) lwsB[e] = lwsA[e] ^ 32;
    stage_store8(smem, dqB, lwsB, smask);
  }
  __builtin_amdgcn_sched_barrier(0);
  if (gvld) {
    const float* sp = out0 + 32 * MN + goffA;           // tile1 subA
    #pragma unroll
    for (int j = 0; j < 8; ++j) dqA[j] = *(const f32x4*)(sp + j * MN);
    const float* sq = out0 + 32 * MN + goffA + 16 * MN; // tile1 subB
    #pragma unroll
    for (int j = 0; j < 8; ++j) dqB[j] = *(const f32x4*)(sq + j * MN);
  }
  __builtin_amdgcn_sched_barrier(0);
  STAGE_W_ALL(0);
  if (wv == 7) asm volatile("s_waitcnt vmcnt(0)" ::: "memory");
  PIPE_BARRIER();

  f32x4 acc[4][4];
  #pragma unroll
  for (int i = 0; i < 4; ++i)
    #pragma unroll
    for (int nt = 0; nt < 4; ++nt)
      acc[i][nt] = (f32x4){0.f, 0.f, 0.f, 0.f};

  #pragma unroll 1
  for (int g = 0; g < 8; ++g) {
    const unsigned short* cur = smem + (g & 1) * BUFU;
    unsigned short*       nxt = smem + ((g + 1) & 1) * BUFU;

    // issue next W group early (wave 7; consumed after this iteration's barrier)
    STAGE_W_ALL(g + 1);
    // store tile(g+1) [loads issued a full iteration ago -> landed]
    if (g < 7) {
      stage_store8(nxt, dqA, lwsA, smask);
      int lwsB[4];
      #pragma unroll
      for (int e = 0; e < 4; ++e) lwsB[e] = lwsA[e] ^ 32;
      stage_store8(nxt, dqB, lwsB, smask);
    }
    __builtin_amdgcn_sched_barrier(0);
    // issue tile(g+2)
    if (g < 6 && gvld) {
      const float* sp = out0 + (g + 2) * (32 * MN) + goffA;
      #pragma unroll
      for (int j = 0; j < 8; ++j) dqA[j] = *(const f32x4*)(sp + j * MN);
      const float* sq = out0 + (g + 2) * (32 * MN) + goffA + 16 * MN;
      #pragma unroll
      for (int j = 0; j < 8; ++j) dqB[j] = *(const f32x4*)(sq + j * MN);
    }
    __builtin_amdgcn_sched_barrier(0);

    // all 9 taps, no intra-iteration barriers
    TAPS3(0)
    TAPS3(1)
    TAPS3(2)

    if (wv == 7) asm volatile("s_waitcnt vmcnt(0)" ::: "memory");
    PIPE_BARRIER();
  }

  // --- epilogue: bias+relu, acc -> LDS [pixel][channel] bf16 (512 x 66) ---
  #define ES 66
  {
    float bias[4];
    #pragma unroll
    for (int nt = 0; nt < 4; ++nt) bias[nt] = mb_b[nt * 16 + n15];
    #pragma unroll
    for (int i = 0; i < 4; ++i) {
      int pbase = (2 * wv + (i >> 1)) * 32 + (i & 1) * 16;
      #pragma unroll
      for (int nt = 0; nt < 4; ++nt)
        #pragma unroll
        for (int reg = 0; reg < 4; ++reg) {
          float vv = fmaxf(acc[i][nt][reg] + bias[nt], 0.f);
          smem[(pbase + kq * 4 + reg) * ES + nt * 16 + n15] = f2bf(vv);
        }
    }
  }
  __syncthreads();

  // dynamic heads: 2 passes of 256 px; thread (p, half) -> pixel, ch-half
  int p = tid & 255, hh = tid >> 8;
  int ob = hh * 32;
  float* pf = (float*)smem + 16896;   // byte 67584, past 512x66 table
  #pragma unroll 1
  for (int ps = 0; ps < 2; ++ps) {
    int pixel = ps * 256 + p;
    float mres[4] = {0.f, 0.f, 0.f, 0.f};
    float rres[4] = {0.f, 0.f, 0.f, 0.f};
    #pragma unroll 8
    for (int o = 0; o < 32; ++o) {
      float v = b2f(smem[pixel * ES + ob + o]);
      #pragma unroll
      for (int i = 0; i < 4; ++i) {
        mres[i] += ws_gp[i * NP + ob + o] * v;
        rres[i] += ws_gp[i * NP + 67 + ob + o] * v;
      }
    }
    if (hh) {
      #pragma unroll
      for (int i = 0; i < 4; ++i) { pf[p * 8 + i] = mres[i]; pf[p * 8 + 4 + i] = rres[i]; }
    }
    __syncthreads();
    if (!hh) {
      int r = pixel >> 5, xcol = pixel & 31;
      int gy = gy0 + r, gx = gx0 + xcol;
      float xc = -1.f + (2.f / 479.f) * (float)gx;
      float yc = -1.f + (2.f / 271.f) * (float)gy;
      int pix = gy * MW + gx;
      #pragma unroll
      for (int i = 0; i < 4; ++i) {
        const float* gp = ws_gp + i * NP;
        d_out[MASK_OFF + i * MN + pix] = mres[i] + pf[p * 8 + i]     + gp[66]  + gp[64]  * xc + gp[65]  * yc;
        d_out[REG_OFF  + i * MN + pix] = rres[i] + pf[p * 8 + 4 + i] + gp[133] + gp[131] * xc + gp[132] * yc;
      }
    }
    __syncthreads();
  }
}

// ------------------------------------------------------------------
// K5: feat_range MLP — column staged in LDS by 64 parallel lanes
// ------------------------------------------------------------------
__global__ void k_mlp(const float* __restrict__ masks0, const float* __restrict__ w1,
                      const float* __restrict__ b1, const float* __restrict__ w2,
                      const float* __restrict__ b2, float* __restrict__ d_out) {
  __shared__ float ms[MH];
  int blk = blockIdx.x;          // i*480 + w
  int i = blk / MW;
  int w = blk - i * MW;
  int k = threadIdx.x;           // 0..63
  const float* mcol = masks0 + i * MN + w;
  for (int h = k; h < MH; h += 64) ms[h] = mcol[h * MW];
  __syncthreads();
  float s = b1[k];
  #pragma unroll 8
  for (int h = 0; h < MH; ++h) s += ms[h] * w1[h * HID + k];
  s = fmaxf(s, 0.f);
  float o0 = s * w2[k * 2 + 0];
  float o1 = s * w2[k * 2 + 1];
  #pragma unroll
  for (int off = 32; off >= 1; off >>= 1) {
    o0 += __shfl_down(o0, off);
    o1 += __shfl_down(o1, off);
  }
  if (k == 0) {
    d_out[FEAT_OFF + blk * 2 + 0] = o0 + b2[0];
    d_out[FEAT_OFF + blk * 2 + 1] = o1 + b2[1];
  }
}

// ------------------------------------------------------------------
extern "C" void kernel_launch(void* const* d_in, const int* in_sizes, int n_in,
                              void* d_out, int out_size, void* d_ws, size_t ws_size,
                              hipStream_t stream) {
  const float* out0     = (const float*)d_in[0];
  const float* out1     = (const float*)d_in[1];
  const float* hm_w     = (const float*)d_in[2];
  const float* hm_b     = (const float*)d_in[3];
  const float* params_w = (const float*)d_in[4];
  const float* params_b = (const float*)d_in[5];
  const float* mb_w     = (const float*)d_in[6];
  const float* mb_b     = (const float*)d_in[7];
  const float* mlp_w1   = (const float*)d_in[8];
  const float* mlp_b1   = (const float*)d_in[9];
  const float* mlp_w2   = (const float*)d_in[10];
  const float* mlp_b2   = (const float*)d_in[11];

  float* ws      = (float*)d_ws;
  float* ws_hm   = ws + WS_HM;
  float* candv   = ws + WS_CV;
  int*   candi   = (int*)(ws + WS_CI);
  float* ws_gp   = ws + WS_GP;
  unsigned short* ws_wt = (unsigned short*)(ws + WS_WT_F);
  float* out     = (float*)d_out;

  k_prep<<<1086, 256, 0, stream>>>(mb_w, ws_wt, out1, hm_w, hm_b, ws_hm);
  k_nms_top<<<128, 256, 0, stream>>>(ws_hm, candv, candi);
  k_gen<<<NI, 512, 0, stream>>>(candv, candi, out1, params_w, params_b, ws_gp, out);
  k_conv_mfma<<<255, 512, 0, stream>>>(out0, ws_wt, mb_b, ws_gp, out);
  k_mlp<<<NI * MW, 64, 0, stream>>>(out + MASK_OFF, mlp_w1, mlp_b1, mlp_w2, mlp_b2, out);
}